// Round 7
// baseline (376.621 us; speedup 1.0000x reference)
//
#include <hip/hip_runtime.h>
#include <hip/hip_bf16.h>
#include <math.h>

// CrossAttention3D: B=1, C=64, N=4096, 8 heads x hd=8.
// ONE kernel, 1024 blocks x 256 threads (exactly 4 blocks/CU at
// __launch_bounds__(256,4): LDS 18.4KB <= 40KB, VGPR <= 128 -> all blocks
// co-resident by construction; software grid barrier, no cooperative API).
//   Phase 1 (blocks 0-255):  QKV projections -> packed bf16 MFMA operands.
//   Phase 2 (all 1024):      MFMA attention (32x32x16 bf16), split-K KS=8.
//     QK: D = A(K) x B(Q) = S^T; KpZ rows = 8 real + 8 zero -> kslots 8-15 dead.
//     softmax: p = exp2(s), no max subtraction (|s| <~ 2.6 base-2).
//     PV: A = P (LDS round-trip, 72B pitch), B = VtP pre-swizzled B-frags;
//         VtP row d=8 = ones -> D col 8 = softmax denominator for free.
//   Phase 3 (blocks 0-255):  split-K combine + output projection fused.
// Barriers: atomic {cnt,gen} in ws (memset to 0 per launch) + __threadfence()
// release/acquire for cross-XCD L2 coherence (G16).

#define N_VOX 4096
#define NH 8
#define KS 8
#define KPS (N_VOX / KS)    // 512 keys per split
#define NBLK 1024
#define QSCALE 0.51010813f  // 8^-0.5 * log2(e)

typedef unsigned short ushort_t;
typedef __attribute__((ext_vector_type(8))) short bf16x8;
typedef __attribute__((ext_vector_type(16))) float f32x16;

__device__ __forceinline__ unsigned short f2bf(float f) {
  union { float f; unsigned u; } v; v.f = f;
  unsigned r = v.u + 0x7FFFu + ((v.u >> 16) & 1u);
  return (unsigned short)(r >> 16);
}
__device__ __forceinline__ unsigned pk2bf(float a, float b) {
  __hip_bfloat162 h = __float22bfloat162_rn(float2{a, b});
  union { __hip_bfloat162 h; unsigned u; } c; c.h = h;
  return c.u;
}
__device__ __forceinline__ float ex2(float x) { return __builtin_amdgcn_exp2f(x); }

// Reusable generation-based grid barrier. All NBLK blocks must call it.
__device__ __forceinline__ void grid_barrier(unsigned* cnt, unsigned* gen,
                                             int tid) {
  __syncthreads();
  if (tid == 0) {
    __threadfence();  // release: drain this block's writes to device scope
    unsigned g = atomicAdd(gen, 0u);   // read gen BEFORE arriving
    unsigned v = atomicAdd(cnt, 1u);
    if (v == NBLK - 1) {
      atomicExch(cnt, 0u);             // reset for next use
      __threadfence();
      atomicAdd(gen, 1u);              // release everyone
    } else {
      while (atomicAdd(gen, 0u) == g) __builtin_amdgcn_s_sleep(4);
    }
    __threadfence();  // acquire: invalidate stale lines before consuming
  }
  __syncthreads();
}

__global__ __launch_bounds__(256, 4) void fused_xattn(
    const float* __restrict__ dec, const float* __restrict__ mae,
    const float* __restrict__ qw, const float* __restrict__ qb_,
    const float* __restrict__ kw, const float* __restrict__ kb,
    const float* __restrict__ vw, const float* __restrict__ vb,
    const float* __restrict__ ow, const float* __restrict__ obias,
    ushort_t* __restrict__ Qp, ushort_t* __restrict__ KpZ,
    ushort_t* __restrict__ VtP, float* __restrict__ o_part,
    unsigned* __restrict__ bar, float* __restrict__ out) {
  const int b = blockIdx.x;
  const int tid = threadIdx.x;
  unsigned* cnt = bar;
  unsigned* gen = bar + 1;

  // P scratch: [wave*2+qtile][q=32 rows][36 ushorts] (72 B pitch -> <=2-way
  // bank aliasing on b64 ops, free per m136).
  __shared__ ushort_t P_lds[8][32 * 36];

  // ------------------------------------------------------------- Phase 1
  if (b < 256) {
    const int bx = b >> 4;  // 0-7: Q(dec) head; 8-15: K+V(mae) head
    const int n = (b & 15) * 256 + tid;
    if (bx < 8) {
      const int h = bx;
      float x[64];
#pragma unroll
      for (int c = 0; c < 64; ++c) x[c] = dec[c * N_VOX + n];
      float qv[8];
#pragma unroll
      for (int j = 0; j < 8; ++j) {
        const int o = h * 8 + j;
        float a = qb_[o];
#pragma unroll
        for (int c = 0; c < 64; ++c) a = fmaf(x[c], qw[o * 64 + c], a);
        qv[j] = a * QSCALE;
      }
      uint4 pk;
      pk.x = pk2bf(qv[0], qv[1]); pk.y = pk2bf(qv[2], qv[3]);
      pk.z = pk2bf(qv[4], qv[5]); pk.w = pk2bf(qv[6], qv[7]);
      *(uint4*)(Qp + ((size_t)h * N_VOX + n) * 8) = pk;
    } else {
      const int h = bx - 8;
      float x[64];
#pragma unroll
      for (int c = 0; c < 64; ++c) x[c] = mae[c * N_VOX + n];
      float kv[8], vv[8];
#pragma unroll
      for (int j = 0; j < 8; ++j) {
        const int o = h * 8 + j;
        float a = kb[o], v = vb[o];
#pragma unroll
        for (int c = 0; c < 64; ++c) {
          a = fmaf(x[c], kw[o * 64 + c], a);
          v = fmaf(x[c], vw[o * 64 + c], v);
        }
        kv[j] = a; vv[j] = v;
      }
      uint4 pk;
      pk.x = pk2bf(kv[0], kv[1]); pk.y = pk2bf(kv[2], kv[3]);
      pk.z = pk2bf(kv[4], kv[5]); pk.w = pk2bf(kv[6], kv[7]);
      ushort_t* krow = KpZ + ((size_t)h * N_VOX + n) * 16;
      *(uint4*)(krow) = pk;
      *(uint4*)(krow + 8) = make_uint4(0, 0, 0, 0);

      // VtP frag layout: [h][kb=key/16][lane][j]; element =
      // V^T[d=lane&31][key=kb*16+(lane>>5)*8+j]; d==8 -> 1.0 (denominator);
      // d=9..31 = ws poison (finite, lands in discarded D cols).
      const size_t base =
          (((size_t)h * (N_VOX / 16) + (n >> 4)) * 64 + ((n >> 3) & 1) * 32) * 8 +
          (n & 7);
#pragma unroll
      for (int d = 0; d < 8; ++d) VtP[base + (size_t)d * 8] = f2bf(vv[d]);
      VtP[base + 8 * 8] = 0x3F80;  // ones row -> denominator
    }
  }

  grid_barrier(cnt, gen, tid);

  // ------------------------------------------------------------- Phase 2
  {
    const int lane = tid & 63;
    const int wave = tid >> 6;
    const int l31 = lane & 31;
    const int lhalf = lane >> 5;
    const int qt = b & 15;
    const int h = (b >> 4) & 7;
    const int ks = b >> 7;
    const int qb = qt * 256 + wave * 64;

    bf16x8 qfrag0 = *(const bf16x8*)(Qp + ((size_t)h * N_VOX + qb + l31) * 8);
    bf16x8 qfrag1 = *(const bf16x8*)(Qp + ((size_t)h * N_VOX + qb + 32 + l31) * 8);

    f32x16 zf, acc0, acc1;
#pragma unroll
    for (int i = 0; i < 16; ++i) { zf[i] = 0.f; acc0[i] = 0.f; acc1[i] = 0.f; }

    const ushort_t* KpH = KpZ + (size_t)h * N_VOX * 16 + lhalf * 8;
    const ushort_t* VtPH = VtP + (size_t)h * (N_VOX / 16) * 64 * 8;
    ushort_t* pb0 = &P_lds[wave * 2 + 0][l31 * 36];
    ushort_t* pb1 = &P_lds[wave * 2 + 1][l31 * 36];
    const int kbeg = ks * KPS;

#pragma unroll 1
    for (int kk = 0; kk < KPS; kk += 32) {
      const int kcur = kbeg + kk;
      bf16x8 kf = *(const bf16x8*)(KpH + (size_t)(kcur + l31) * 16);
      bf16x8 vf0 = *(const bf16x8*)(VtPH + ((size_t)((kcur >> 4) + 0) * 64 + lane) * 8);
      bf16x8 vf1 = *(const bf16x8*)(VtPH + ((size_t)((kcur >> 4) + 1) * 64 + lane) * 8);

      f32x16 s0 = __builtin_amdgcn_mfma_f32_32x32x16_bf16(kf, qfrag0, zf, 0, 0, 0);
      f32x16 s1 = __builtin_amdgcn_mfma_f32_32x32x16_bf16(kf, qfrag1, zf, 0, 0, 0);

#pragma unroll
      for (int G = 0; G < 4; ++G) {
        uint2 w;
        w.x = pk2bf(ex2(s0[G * 4 + 0]), ex2(s0[G * 4 + 1]));
        w.y = pk2bf(ex2(s0[G * 4 + 2]), ex2(s0[G * 4 + 3]));
        *(uint2*)(pb0 + G * 8 + lhalf * 4) = w;
      }
#pragma unroll
      for (int G = 0; G < 4; ++G) {
        uint2 w;
        w.x = pk2bf(ex2(s1[G * 4 + 0]), ex2(s1[G * 4 + 1]));
        w.y = pk2bf(ex2(s1[G * 4 + 2]), ex2(s1[G * 4 + 3]));
        *(uint2*)(pb1 + G * 8 + lhalf * 4) = w;
      }

#pragma unroll
      for (int grp = 0; grp < 2; ++grp) {
        union { bf16x8 v; uint2 u[2]; } p0, p1;
        p0.u[0] = *(const uint2*)(pb0 + grp * 16 + lhalf * 8);
        p0.u[1] = *(const uint2*)(pb0 + grp * 16 + lhalf * 8 + 4);
        p1.u[0] = *(const uint2*)(pb1 + grp * 16 + lhalf * 8);
        p1.u[1] = *(const uint2*)(pb1 + grp * 16 + lhalf * 8 + 4);
        const bf16x8 vf = grp ? vf1 : vf0;
        acc0 = __builtin_amdgcn_mfma_f32_32x32x16_bf16(p0.v, vf, acc0, 0, 0, 0);
        acc1 = __builtin_amdgcn_mfma_f32_32x32x16_bf16(p1.v, vf, acc1, 0, 0, 0);
      }
    }

    // Epilogue: D col (l31) = d 0-7, col 8 = denominator; rows = q.
    if (l31 < 9) {
      float* ob = o_part + ((size_t)(ks * NH + h) * 9 + l31) * N_VOX;
#pragma unroll
      for (int t = 0; t < 2; ++t) {
        const f32x16 a = t ? acc1 : acc0;
        const int qst = qb + t * 32 + 4 * lhalf;
#pragma unroll
        for (int G = 0; G < 4; ++G) {
          float4 v4 = make_float4(a[G * 4 + 0], a[G * 4 + 1], a[G * 4 + 2], a[G * 4 + 3]);
          *(float4*)(ob + qst + 8 * G) = v4;
        }
      }
    }
  }

  grid_barrier(cnt, gen, tid);

  // ------------------------------------------------------------- Phase 3
  // blocks 0-255: og = b>>4 (4 out-channels each), n = (b&15)*256 + tid.
  if (b < 256) {
    const int og = b >> 4;
    const int n = (b & 15) * 256 + tid;

    // Per-head softmax denominators (sum over splits of D col 8).
    float rinv[NH];
#pragma unroll
    for (int h = 0; h < NH; ++h) {
      float l = 0.f;
#pragma unroll
      for (int s = 0; s < KS; ++s)
        l += o_part[((size_t)(s * NH + h) * 9 + 8) * N_VOX + n];
      rinv[h] = 1.0f / l;
    }

    float acc[4];
#pragma unroll
    for (int j = 0; j < 4; ++j) acc[j] = obias[og * 4 + j];

#pragma unroll 2
    for (int c = 0; c < 64; ++c) {
      const int h = c >> 3, d = c & 7;
      float so = 0.f;
#pragma unroll
      for (int s = 0; s < KS; ++s)
        so += o_part[((size_t)(s * NH + h) * 9 + d) * N_VOX + n];
      const float x = so * rinv[h];
#pragma unroll
      for (int j = 0; j < 4; ++j)
        acc[j] = fmaf(x, ow[(og * 4 + j) * 64 + c], acc[j]);
    }
#pragma unroll
    for (int j = 0; j < 4; ++j) out[(size_t)(og * 4 + j) * N_VOX + n] = acc[j];
  }
}

// ---------------------------------------------------------------------------
extern "C" void kernel_launch(void* const* d_in, const int* in_sizes, int n_in,
                              void* d_out, int out_size, void* d_ws, size_t ws_size,
                              hipStream_t stream) {
  const float* dec = (const float*)d_in[0];
  const float* mae = (const float*)d_in[1];
  const float* qw = (const float*)d_in[2];
  const float* qb = (const float*)d_in[3];
  const float* kw = (const float*)d_in[4];
  const float* kb = (const float*)d_in[5];
  const float* vw = (const float*)d_in[6];
  const float* vb = (const float*)d_in[7];
  const float* ow = (const float*)d_in[8];
  const float* ob = (const float*)d_in[9];
  float* out = (float*)d_out;
  char* ws = (char*)d_ws;

  const size_t OFF_QP = 0;            // Qp: 8*4096*8*2   = 512 KB
  const size_t OFF_KP = 0x80000;      // KpZ: 8*4096*16*2 = 1 MB
  const size_t OFF_VT = 0x180000;     // VtP: 8*256*64*8*2 = 2 MB
  const size_t OFF_OPART = 0x380000;  // KS*NH*9*N*4 = 9.4 MB
  const size_t OFF_BAR = OFF_OPART + (size_t)KS * NH * 9 * N_VOX * 4;

  ushort_t* Qp = (ushort_t*)(ws + OFF_QP);
  ushort_t* KpZ = (ushort_t*)(ws + OFF_KP);
  ushort_t* VtP = (ushort_t*)(ws + OFF_VT);
  float* o_part = (float*)(ws + OFF_OPART);
  unsigned* bar = (unsigned*)(ws + OFF_BAR);

  // Zero the barrier {cnt,gen} pair (ws is poisoned 0xAA before every call).
  hipMemsetAsync(bar, 0, 2 * sizeof(unsigned), stream);

  fused_xattn<<<dim3(NBLK), dim3(256), 0, stream>>>(
      dec, mae, qw, qb, kw, kb, vw, vb, ow, ob,
      Qp, KpZ, VtP, o_part, bar, out);
}

// Round 8
// 133.360 us; speedup vs baseline: 2.8241x; 2.8241x over previous
//
#include <hip/hip_runtime.h>
#include <hip/hip_bf16.h>
#include <math.h>

// CrossAttention3D: B=1, C=64, N=4096, 8 heads x hd=8.
// Four kernels (fusion via grid barrier disproven in R5/R7 — launch gaps are
// cheaper than cross-XCD barrier spins):
//  1) qkv_pack: projections -> packed bf16 MFMA operand layouts.
//     KpZ[key][16] = 8 real + 8 zeros -> QK A-frag = one b128 coalesced load.
//     VtP = pre-swizzled PV B-frags; row d=8 = ones -> denominator for free.
//  2) attn_mfma: 32 q per wave (not 64) -> ~55 VGPR -> __launch_bounds__(256,8)
//     holds 8 blocks/CU = 32 waves/CU (max occupancy) to hide the
//     exp2->pack->LDS->MFMA chain. Grid (32,8,KS=8) = 2048 blocks = 8/CU.
//  3) combine: split-K reduce, [c][n] output.  4) out_proj.

#define N_VOX 4096
#define NH 8
#define KS 8
#define KPS (N_VOX / KS)    // 512 keys per split
#define QSCALE 0.51010813f  // 8^-0.5 * log2(e)

typedef unsigned short ushort_t;
typedef __attribute__((ext_vector_type(8))) short bf16x8;
typedef __attribute__((ext_vector_type(16))) float f32x16;

__device__ __forceinline__ unsigned short f2bf(float f) {
  union { float f; unsigned u; } v; v.f = f;
  unsigned r = v.u + 0x7FFFu + ((v.u >> 16) & 1u);
  return (unsigned short)(r >> 16);
}
__device__ __forceinline__ unsigned pk2bf(float a, float b) {
  __hip_bfloat162 h = __float22bfloat162_rn(float2{a, b});
  union { __hip_bfloat162 h; unsigned u; } c; c.h = h;
  return c.u;
}
__device__ __forceinline__ float ex2(float x) { return __builtin_amdgcn_exp2f(x); }

// ---------------------------------------------------------------------------
// Kernel 1: projections. grid (16, 16) x 256: bx 0-7 Q(dec) head, 8-15 K+V(mae).
__global__ __launch_bounds__(256) void qkv_pack(
    const float* __restrict__ dec, const float* __restrict__ mae,
    const float* __restrict__ qw, const float* __restrict__ qb_,
    const float* __restrict__ kw, const float* __restrict__ kb,
    const float* __restrict__ vw, const float* __restrict__ vb,
    ushort_t* __restrict__ Qp, ushort_t* __restrict__ KpZ,
    ushort_t* __restrict__ VtP) {
  const int bx = blockIdx.x;
  const int n = blockIdx.y * 256 + threadIdx.x;

  if (bx < 8) {
    const int h = bx;
    float x[64];
#pragma unroll
    for (int c = 0; c < 64; ++c) x[c] = dec[c * N_VOX + n];
    float qv[8];
#pragma unroll
    for (int j = 0; j < 8; ++j) {
      const int o = h * 8 + j;
      float a = qb_[o];
#pragma unroll
      for (int c = 0; c < 64; ++c) a = fmaf(x[c], qw[o * 64 + c], a);
      qv[j] = a * QSCALE;  // fold hd^-0.5 * log2(e) into Q
    }
    uint4 pk;
    pk.x = pk2bf(qv[0], qv[1]); pk.y = pk2bf(qv[2], qv[3]);
    pk.z = pk2bf(qv[4], qv[5]); pk.w = pk2bf(qv[6], qv[7]);
    *(uint4*)(Qp + ((size_t)h * N_VOX + n) * 8) = pk;
  } else {
    const int h = bx - 8;
    float x[64];
#pragma unroll
    for (int c = 0; c < 64; ++c) x[c] = mae[c * N_VOX + n];
    float kv[8], vv[8];
#pragma unroll
    for (int j = 0; j < 8; ++j) {
      const int o = h * 8 + j;
      float a = kb[o], v = vb[o];
#pragma unroll
      for (int c = 0; c < 64; ++c) {
        a = fmaf(x[c], kw[o * 64 + c], a);
        v = fmaf(x[c], vw[o * 64 + c], v);
      }
      kv[j] = a; vv[j] = v;
    }
    // KpZ row: [8 bf16 K values][8 zeros] (zeros feed MFMA kslots 8-15).
    uint4 pk;
    pk.x = pk2bf(kv[0], kv[1]); pk.y = pk2bf(kv[2], kv[3]);
    pk.z = pk2bf(kv[4], kv[5]); pk.w = pk2bf(kv[6], kv[7]);
    ushort_t* krow = KpZ + ((size_t)h * N_VOX + n) * 16;
    *(uint4*)(krow) = pk;
    *(uint4*)(krow + 8) = make_uint4(0, 0, 0, 0);

    // VtP frag layout: [h][kb=key/16][lane][j]; element =
    // V^T[d=lane&31][key=kb*16+(lane>>5)*8+j]; d==8 -> 1.0 (denominator);
    // d=9..31 = ws poison (finite, lands in discarded D cols).
    const size_t base =
        (((size_t)h * (N_VOX / 16) + (n >> 4)) * 64 + ((n >> 3) & 1) * 32) * 8 +
        (n & 7);
#pragma unroll
    for (int d = 0; d < 8; ++d) VtP[base + (size_t)d * 8] = f2bf(vv[d]);
    VtP[base + 8 * 8] = 0x3F80;  // ones row -> denominator
  }
}

// ---------------------------------------------------------------------------
// Kernel 2: MFMA attention. grid (32, 8, KS) x 256; 4 waves, 32 q per wave.
// 32-q tile keeps one f32x16 acc + one S tile -> ~55 VGPR -> 8 blocks/CU.
__global__ __launch_bounds__(256, 8) void attn_mfma(
    const ushort_t* __restrict__ Qp, const ushort_t* __restrict__ KpZ,
    const ushort_t* __restrict__ VtP, float* __restrict__ o_part) {
  const int tid = threadIdx.x;
  const int lane = tid & 63;
  const int wave = tid >> 6;
  const int l31 = lane & 31;
  const int lhalf = lane >> 5;
  const int h = blockIdx.y;
  const int ks = blockIdx.z;
  const int qb = blockIdx.x * 128 + wave * 32;

  // P scratch: [wave][q=32 rows][36 ushorts] (72 B pitch -> <=2-way bank
  // aliasing on b64 ops, free per m136).  4 x 2304 B = 9216 B.
  __shared__ ushort_t P_lds[4][32 * 36];

  bf16x8 qfrag = *(const bf16x8*)(Qp + ((size_t)h * N_VOX + qb + l31) * 8);

  f32x16 acc;
#pragma unroll
  for (int i = 0; i < 16; ++i) acc[i] = 0.f;
  f32x16 zf;
#pragma unroll
  for (int i = 0; i < 16; ++i) zf[i] = 0.f;

  const ushort_t* KpH = KpZ + (size_t)h * N_VOX * 16 + lhalf * 8;
  const ushort_t* VtPH = VtP + (size_t)h * (N_VOX / 16) * 64 * 8;
  ushort_t* pb = &P_lds[wave][l31 * 36];
  const int kbeg = ks * KPS;

#pragma unroll 1
  for (int kk = 0; kk < KPS; kk += 32) {
    const int kcur = kbeg + kk;
    // A-frag: A[m=key=l31][k=lhalf*8+j] -> one coalesced b128 per lane.
    bf16x8 kf = *(const bf16x8*)(KpH + (size_t)(kcur + l31) * 16);
    bf16x8 vf0 = *(const bf16x8*)(VtPH + ((size_t)((kcur >> 4) + 0) * 64 + lane) * 8);
    bf16x8 vf1 = *(const bf16x8*)(VtPH + ((size_t)((kcur >> 4) + 1) * 64 + lane) * 8);

    // S^T tile [32k x 32q]: rows=keys, cols=q (lane col = q = l31).
    f32x16 s = __builtin_amdgcn_mfma_f32_32x32x16_bf16(kf, qfrag, zf, 0, 0, 0);

    // p = exp2(s); store P[q][key_local].
#pragma unroll
    for (int G = 0; G < 4; ++G) {
      uint2 w;
      w.x = pk2bf(ex2(s[G * 4 + 0]), ex2(s[G * 4 + 1]));
      w.y = pk2bf(ex2(s[G * 4 + 2]), ex2(s[G * 4 + 3]));
      *(uint2*)(pb + G * 8 + lhalf * 4) = w;
    }

    // PV: A = P[m=q][k=key_local], B = VtP frag (n=d, k=key_local).
#pragma unroll
    for (int grp = 0; grp < 2; ++grp) {
      union { bf16x8 v; uint2 u[2]; } p;
      p.u[0] = *(const uint2*)(pb + grp * 16 + lhalf * 8);
      p.u[1] = *(const uint2*)(pb + grp * 16 + lhalf * 8 + 4);
      acc = __builtin_amdgcn_mfma_f32_32x32x16_bf16(p.v, grp ? vf1 : vf0, acc,
                                                    0, 0, 0);
    }
  }

  // Epilogue: D col (l31) = d 0-7, col 8 = denominator; rows = q.
  if (l31 < 9) {
    float* ob = o_part + ((size_t)(ks * NH + h) * 9 + l31) * N_VOX;
    const int qst = qb + 4 * lhalf;
#pragma unroll
    for (int G = 0; G < 4; ++G) {
      float4 v4 = make_float4(acc[G * 4 + 0], acc[G * 4 + 1], acc[G * 4 + 2],
                              acc[G * 4 + 3]);
      *(float4*)(ob + qst + 8 * G) = v4;
    }
  }
}

// ---------------------------------------------------------------------------
// Kernel 3: combine split-K partials: ocomb[c][n] = sum_o / sum_l. grid 1024x256.
__global__ __launch_bounds__(256) void combine(
    const float* __restrict__ o_part, float* __restrict__ ocomb) {
  const int t = blockIdx.x * 256 + threadIdx.x;
  const int c = t >> 12, n = t & (N_VOX - 1);
  const int h = c >> 3, d = c & 7;
  float so = 0.f, sl = 0.f;
#pragma unroll
  for (int s = 0; s < KS; ++s) {
    const float* base = o_part + ((size_t)(s * NH + h) * 9) * N_VOX;
    so += base[d * N_VOX + n];
    sl += base[8 * N_VOX + n];
  }
  ocomb[(size_t)c * N_VOX + n] = so / sl;
}

// ---------------------------------------------------------------------------
// Kernel 4: output projection (fp32). grid (8, 16) x 256; coalesced reads.
__global__ __launch_bounds__(256) void out_proj(
    const float* __restrict__ ocomb, const float* __restrict__ ow,
    const float* __restrict__ obias, float* __restrict__ out) {
  const int og = blockIdx.x;
  const int n = blockIdx.y * 256 + threadIdx.x;
  float x[64];
#pragma unroll
  for (int c = 0; c < 64; ++c) x[c] = ocomb[c * N_VOX + n];
#pragma unroll
  for (int j = 0; j < 8; ++j) {
    const int o = og * 8 + j;
    float acc = obias[o];
#pragma unroll
    for (int c = 0; c < 64; ++c) acc = fmaf(x[c], ow[o * 64 + c], acc);
    out[o * N_VOX + n] = acc;
  }
}

// ---------------------------------------------------------------------------
extern "C" void kernel_launch(void* const* d_in, const int* in_sizes, int n_in,
                              void* d_out, int out_size, void* d_ws, size_t ws_size,
                              hipStream_t stream) {
  const float* dec = (const float*)d_in[0];
  const float* mae = (const float*)d_in[1];
  const float* qw = (const float*)d_in[2];
  const float* qb = (const float*)d_in[3];
  const float* kw = (const float*)d_in[4];
  const float* kb = (const float*)d_in[5];
  const float* vw = (const float*)d_in[6];
  const float* vb = (const float*)d_in[7];
  const float* ow = (const float*)d_in[8];
  const float* ob = (const float*)d_in[9];
  float* out = (float*)d_out;
  char* ws = (char*)d_ws;

  const size_t OFF_QP = 0;            // Qp: 8*4096*8*2   = 512 KB
  const size_t OFF_KP = 0x80000;      // KpZ: 8*4096*16*2 = 1 MB
  const size_t OFF_VT = 0x180000;     // VtP: 8*256*64*8*2 = 2 MB
  const size_t OFF_OPART = 0x380000;  // KS*NH*9*N*4 = 9.4 MB
  const size_t OFF_OCOMB = OFF_OPART + (size_t)KS * NH * 9 * N_VOX * 4;

  ushort_t* Qp = (ushort_t*)(ws + OFF_QP);
  ushort_t* KpZ = (ushort_t*)(ws + OFF_KP);
  ushort_t* VtP = (ushort_t*)(ws + OFF_VT);
  float* o_part = (float*)(ws + OFF_OPART);
  float* ocomb = (float*)(ws + OFF_OCOMB);

  qkv_pack<<<dim3(16, 16), 256, 0, stream>>>(dec, mae, qw, qb, kw, kb, vw, vb,
                                             Qp, KpZ, VtP);
  attn_mfma<<<dim3(32, 8, KS), 256, 0, stream>>>(Qp, KpZ, VtP, o_part);
  combine<<<1024, 256, 0, stream>>>(o_part, ocomb);
  out_proj<<<dim3(8, 16), 256, 0, stream>>>(ocomb, ow, ob, out);
}